// Round 3
// baseline (808.243 us; speedup 1.0000x reference)
//
#include <hip/hip_runtime.h>
#include <hip/hip_bf16.h>

#define DK 256      // inner dim (d)
#define EPSV 1e-6f
#define CHUNK 256   // rows per chunk = 16 waves x 16 rows
#define GGRID 256   // k_gemm grid (1 block/CU)

typedef __bf16 bf16x8 __attribute__((ext_vector_type(8)));
typedef __bf16 bf16x4 __attribute__((ext_vector_type(4)));
typedef float f32x4 __attribute__((ext_vector_type(4)));

// ws layout (floats): [0..31] Usum, [32..63] s, [64..1087] VtZ, [1088] D
//                     [4096 .. 4096+GGRID*1024) per-block VtZ partials

// LDS layout (bytes):
//   [0, 65536)          W as bf16 MFMA B-fragments (4096 frags x 16 B)
//   [65536, 147456)     per-wave strips: wave w at 65536 + w*5120:
//                         Vs: 32 cols x 40-row pitch bf16 (2560 B), rows 16..31 zero-pad
//                         Zs: same, at +2560 B
//   after chunk loop (strips dead): vtzL f32[1024] at 65536, redS f32[64] at +4096

__global__ __launch_bounds__(1024) void k_gemm(
    const float* __restrict__ x, const float* __restrict__ W,
    const float* __restrict__ bias, float* __restrict__ out,
    float* __restrict__ accg, int N)
{
  __shared__ __align__(16) unsigned char smem[147456];
  __bf16* Wlds = (__bf16*)smem;

  const int tid  = threadIdx.x;
  const int wave = tid >> 6;
  const int lane = tid & 63;
  const int quad = lane >> 4;
  const int l16  = lane & 15;

  __bf16* Vsw = (__bf16*)(smem + 65536 + wave * 5120);
  __bf16* Zsw = Vsw + 1280;

  // zero this wave's strips (incl. K-pad rows 16..31, which stay zero forever)
  for (int i = lane; i < 2560; i += 64) Vsw[i] = (__bf16)0.f;

  // stage W into LDS as bf16 fragments: frag f = (kk*4+quad)*128 + n
  for (int f = tid; f < 4096; f += 1024) {
    const int n  = f & 127;
    const int qk = f >> 7;
    const int k0 = (qk >> 2) * 32 + (qk & 3) * 8;
    bf16x8 w;
    #pragma unroll
    for (int j = 0; j < 8; ++j) w[j] = (__bf16)W[(size_t)(k0 + j) * 128 + n];
    *(bf16x8*)&Wlds[f * 8] = w;
  }
  float bias8[8];
  #pragma unroll
  for (int ntl = 0; ntl < 8; ++ntl) bias8[ntl] = bias[ntl * 16 + l16];
  __syncthreads();          // the ONLY barrier before the final reduction

  float usum[2] = {0.f, 0.f};
  float ssum[2] = {0.f, 0.f};
  f32x4 vtz[2][2];
  #pragma unroll
  for (int mt = 0; mt < 2; ++mt)
    #pragma unroll
    for (int nt = 0; nt < 2; ++nt) vtz[mt][nt] = (f32x4){0.f, 0.f, 0.f, 0.f};

  const int nch = (N + CHUNK - 1) / CHUNK;
  for (int c = blockIdx.x; c < nch; c += gridDim.x) {
    const int rbase = c * CHUNK + wave * 16;   // this wave's 16-row slice
    const int arow  = rbase + l16;             // A m = l16
    const bool rv   = arow < N;
    const float* xr = x + (size_t)arow * DK;

    // ---- group 0 loads (kk 0..3): 8 dwordx4 ----
    f32x4 xa[8];
    #pragma unroll
    for (int t = 0; t < 8; ++t)
      xa[t] = rv ? *(const f32x4*)(xr + (t >> 1) * 32 + quad * 8 + (t & 1) * 4)
                 : (f32x4){0.f, 0.f, 0.f, 0.f};

    f32x4 acc[8];
    #pragma unroll
    for (int t = 0; t < 8; ++t) acc[t] = (f32x4){0.f, 0.f, 0.f, 0.f};

    // convert g0 to bf16 (waits xa), then issue g1 loads so they fly during g0 MFMAs
    bf16x8 afa[4];
    #pragma unroll
    for (int kk = 0; kk < 4; ++kk) {
      const f32x4 lo = xa[2 * kk], hi = xa[2 * kk + 1];
      bf16x8 f;
      f[0] = (__bf16)lo.x; f[1] = (__bf16)lo.y; f[2] = (__bf16)lo.z; f[3] = (__bf16)lo.w;
      f[4] = (__bf16)hi.x; f[5] = (__bf16)hi.y; f[6] = (__bf16)hi.z; f[7] = (__bf16)hi.w;
      afa[kk] = f;
    }
    f32x4 xb[8];
    #pragma unroll
    for (int t = 0; t < 8; ++t)
      xb[t] = rv ? *(const f32x4*)(xr + 128 + (t >> 1) * 32 + quad * 8 + (t & 1) * 4)
                 : (f32x4){0.f, 0.f, 0.f, 0.f};

    // ---- MFMA group 0 ----
    #pragma unroll
    for (int kk = 0; kk < 4; ++kk) {
      #pragma unroll
      for (int ntl = 0; ntl < 8; ++ntl) {
        const bf16x8 bf = *(const bf16x8*)&Wlds[(((kk * 4 + quad) * 128)
                                                + ntl * 16 + l16) * 8];
        acc[ntl] = __builtin_amdgcn_mfma_f32_16x16x32_bf16(afa[kk], bf, acc[ntl], 0, 0, 0);
      }
    }
    // ---- MFMA group 1 ----
    #pragma unroll
    for (int kk = 4; kk < 8; ++kk) {
      const f32x4 lo = xb[2 * (kk - 4)], hi = xb[2 * (kk - 4) + 1];
      bf16x8 f;
      f[0] = (__bf16)lo.x; f[1] = (__bf16)lo.y; f[2] = (__bf16)lo.z; f[3] = (__bf16)lo.w;
      f[4] = (__bf16)hi.x; f[5] = (__bf16)hi.y; f[6] = (__bf16)hi.z; f[7] = (__bf16)hi.w;
      #pragma unroll
      for (int ntl = 0; ntl < 8; ++ntl) {
        const bf16x8 bf = *(const bf16x8*)&Wlds[(((kk * 4 + quad) * 128)
                                                + ntl * 16 + l16) * 8];
        acc[ntl] = __builtin_amdgcn_mfma_f32_16x16x32_bf16(f, bf, acc[ntl], 0, 0, 0);
      }
    }

    // ---- epilogue (C/D: col = l16, row = quad*4 + r) — no barriers ----
    const int g0r = rbase + quad * 4;
    #pragma unroll
    for (int ntl = 0; ntl < 8; ++ntl) {
      float v[4];
      #pragma unroll
      for (int r = 0; r < 4; ++r) {
        float t = fmaxf(acc[ntl][r] + bias8[ntl], 0.f);
        v[r] = (g0r + r < N) ? t : 0.f;
      }
      if (ntl < 2) {                       // U -> out cols 0..31 (parked for k_res)
        #pragma unroll
        for (int r = 0; r < 4; ++r)
          if (g0r + r < N) out[(size_t)(g0r + r) * 64 + ntl * 16 + l16] = v[r];
        usum[ntl] += v[0] + v[1] + v[2] + v[3];
      } else if (ntl < 4) {                // V -> own strip (col-major, bf16)
        ssum[ntl - 2] += v[0] + v[1] + v[2] + v[3];
        bf16x4 p;
        p[0] = (__bf16)v[0]; p[1] = (__bf16)v[1]; p[2] = (__bf16)v[2]; p[3] = (__bf16)v[3];
        *(bf16x4*)&Vsw[((ntl - 2) * 16 + l16) * 40 + quad * 4] = p;
      } else if (ntl < 6) {                // Z -> own strip
        bf16x4 p;
        p[0] = (__bf16)v[0]; p[1] = (__bf16)v[1]; p[2] = (__bf16)v[2]; p[3] = (__bf16)v[3];
        *(bf16x4*)&Zsw[((ntl - 4) * 16 + l16) * 40 + quad * 4] = p;
      } else {                             // T -> out cols 32..63
        #pragma unroll
        for (int r = 0; r < 4; ++r)
          if (g0r + r < N) out[(size_t)(g0r + r) * 64 + 32 + (ntl - 6) * 16 + l16] = v[r];
      }
    }

    // VtZ += Vw^T @ Zw via 4 zero-padded 16x16x32 MFMAs (in-wave LDS round-trip,
    // lgkmcnt-ordered — no barrier). A[m=l16][k=quad*8+j]: rows >=16 are zero pad.
    #pragma unroll
    for (int mt = 0; mt < 2; ++mt) {
      const bf16x8 av = *(const bf16x8*)&Vsw[(mt * 16 + l16) * 40 + quad * 8];
      #pragma unroll
      for (int nt = 0; nt < 2; ++nt) {
        const bf16x8 bz = *(const bf16x8*)&Zsw[(nt * 16 + l16) * 40 + quad * 8];
        vtz[mt][nt] = __builtin_amdgcn_mfma_f32_16x16x32_bf16(av, bz, vtz[mt][nt], 0, 0, 0);
      }
    }
  }

  // ---- final block reduction (strips dead -> overlay) ----
  __syncthreads();
  float* vtzL = (float*)(smem + 65536);
  float* redS = vtzL + 1024;
  vtzL[tid] = 0.f;
  if (tid < 64) redS[tid] = 0.f;
  __syncthreads();
  atomicAdd(&redS[l16],      usum[0]);
  atomicAdd(&redS[16 + l16], usum[1]);
  atomicAdd(&redS[32 + l16], ssum[0]);
  atomicAdd(&redS[48 + l16], ssum[1]);
  #pragma unroll
  for (int mt = 0; mt < 2; ++mt)
    #pragma unroll
    for (int nt = 0; nt < 2; ++nt)
      #pragma unroll
      for (int r = 0; r < 4; ++r)
        atomicAdd(&vtzL[(mt * 16 + quad * 4 + r) * 32 + nt * 16 + l16], vtz[mt][nt][r]);
  __syncthreads();
  if (tid < 64) atomicAdd(&accg[tid], redS[tid]);
  accg[4096 + blockIdx.x * 1024 + tid] = vtzL[tid];   // coalesced partial store
}

// Reduce per-block VtZ partials -> accg[64..1087]; block 0 also computes D.
__global__ __launch_bounds__(256) void k_red(float* __restrict__ accg, int N, int nblocks) {
  const int gid = blockIdx.x * 256 + threadIdx.x;   // grid 4 -> gid 0..1023
  const float* part = accg + 4096;
  float a = 0.f;
  #pragma unroll 8
  for (int b = 0; b < nblocks; ++b) a += part[b * 1024 + gid];
  accg[64 + gid] = a;
  if (blockIdx.x == 0 && threadIdx.x < 64) {
    const int l = threadIdx.x;
    float p = (l < 32) ? accg[l] * accg[32 + l] : 0.f;
    #pragma unroll
    for (int off = 32; off >= 1; off >>= 1) p += __shfl_down(p, off);
    if (l == 0) accg[1088] = 1.0f / (p / (float)N + EPSV);
  }
}

// out[:,0:32] = U @ (VtZ * D), in place (U parked there). One block per 64 rows.
__global__ __launch_bounds__(256) void k_res(float* __restrict__ out,
                                             const float* __restrict__ accg, int N) {
  __shared__ float Ms[32 * 33];
  __shared__ float Us[64 * 33];
  const float D = accg[1088];
  for (int i = threadIdx.x; i < 1024; i += 256)
    Ms[(i >> 5) * 33 + (i & 31)] = accg[64 + i] * D;
  const int j  = threadIdx.x & 31;
  const int r0 = threadIdx.x >> 5;
  const int rbase = blockIdx.x * 64;
  #pragma unroll
  for (int i = 0; i < 8; ++i) {
    const int lr = r0 + i * 8;
    const int row = rbase + lr;
    Us[lr * 33 + j] = (row < N) ? out[(size_t)row * 64 + j] : 0.f;
  }
  __syncthreads();
  #pragma unroll
  for (int i = 0; i < 8; ++i) {
    const int lr = r0 + i * 8;
    const int row = rbase + lr;
    if (row < N) {
      float a = 0.f;
      #pragma unroll
      for (int k = 0; k < 32; ++k) a += Us[lr * 33 + k] * Ms[k * 33 + j];
      out[(size_t)row * 64 + j] = a;
    }
  }
}

extern "C" void kernel_launch(void* const* d_in, const int* in_sizes, int n_in,
                              void* d_out, int out_size, void* d_ws, size_t ws_size,
                              hipStream_t stream) {
  const float* x    = (const float*)d_in[0];
  const float* W    = (const float*)d_in[1];
  const float* b    = (const float*)d_in[2];
  float* out  = (float*)d_out;
  float* accg = (float*)d_ws;
  const int N = in_sizes[0] / DK;
  const int ngroups = (N + 63) >> 6;

  hipMemsetAsync(accg, 0, 1089 * sizeof(float), stream);
  hipLaunchKernelGGL(k_gemm, dim3(GGRID),   dim3(1024), 0, stream, x, W, b, out, accg, N);
  hipLaunchKernelGGL(k_red,  dim3(4),       dim3(256),  0, stream, accg, N, GGRID);
  hipLaunchKernelGGL(k_res,  dim3(ngroups), dim3(256),  0, stream, out, accg, N);
}